// Round 14
// baseline (142.033 us; speedup 1.0000x reference)
//
#include <hip/hip_runtime.h>
#include <stdint.h>

// Problem constants
constexpr int ROWS = 64;
constexpr int D = 1 << 19;             // 524288 per row
constexpr uint32_t KSEL = 52428;       // int(0.1 * D)
constexpr int MBPR = 32;               // blocks per row for streaming kernels
constexpr int MCHUNK = D / MBPR;       // 16384 elements per block
constexpr int LBUF = 896;              // per-block slot cap (expected ~352, +29 sigma)
constexpr uint32_t PRED_B = 0xBFAu;    // key bucket of floats [1.25, 1.375);
                                       // K-th largest = 1.2816 +- 0.0024 (13/39 sigma margin)
constexpr uint32_t NCAND_MAX = 12288;  // per-row candidate cap (expected ~11.3K)

// Workspace layout (u32 words). No zeroing needed: counts plain-stored fresh
// every call; slots read only up to their stored count; thr rewritten always.
constexpr size_t OFF_SCNT = 0;         // [2048] per-block candidate count (raw)
constexpr size_t OFF_ACNT = 2048;      // [2048] per-block above-bucket count
constexpr size_t OFF_THR  = 4096;      // [64] exact threshold key per row
constexpr size_t OFF_PAIR = 4160;      // [2048][2*LBUF]: keys[LBUF] then idx[LBUF]

typedef float f32x4 __attribute__((ext_vector_type(4)));

// Monotonic key: larger float -> larger uint
__device__ __forceinline__ uint32_t mono(uint32_t f) {
    uint32_t m = (uint32_t)((int32_t)f >> 31) | 0x80000000u;
    return f ^ m;
}

// Kernel 1 (read-only): per-block candidate collection (bucket == PRED_B)
// + above-bucket count. IDEMPOTENT: rewrites all its outputs every launch,
// so it can be replicated for timing ablation.
__global__ __launch_bounds__(256) void cand_scan(const uint32_t* __restrict__ x,
                                                 uint32_t* __restrict__ ws) {
    __shared__ uint32_t lkey[LBUF];
    __shared__ uint32_t lidx[LBUF];
    __shared__ uint32_t red[256];
    __shared__ uint32_t ln;
    if (threadIdx.x == 0) ln = 0;
    __syncthreads();
    const int bid = blockIdx.x;
    const int row = bid / MBPR, chunk = bid % MBPR, t = threadIdx.x;
    const uint4* __restrict__ p = (const uint4*)(x + (size_t)row * D + (size_t)chunk * MCHUNK);
    uint32_t above = 0;
    for (int i = t; i < MCHUNK / 4; i += 256) {
        uint4 v = p[i];
        uint32_t idx0 = (uint32_t)chunk * MCHUNK + (uint32_t)i * 4;
#define CLS(comp, j)                                                       \
        {                                                                  \
            uint32_t u = mono(comp);                                       \
            uint32_t bu = u >> 20;                                         \
            above += (bu > PRED_B);                                        \
            if (bu == PRED_B) {                                            \
                uint32_t s = atomicAdd(&ln, 1u);                           \
                if (s < (uint32_t)LBUF) { lkey[s] = u; lidx[s] = idx0 + j; } \
            }                                                              \
        }
        CLS(v.x, 0) CLS(v.y, 1) CLS(v.z, 2) CLS(v.w, 3)
#undef CLS
    }
    red[t] = above;
    __syncthreads();
    for (int off = 128; off > 0; off >>= 1) {
        if (t < off) red[t] += red[t + off];
        __syncthreads();
    }
    if (t == 0) {
        ws[OFF_SCNT + bid] = ln;       // raw count (may exceed LBUF -> fallback)
        ws[OFF_ACNT + bid] = red[0];
    }
    uint32_t m = ln < (uint32_t)LBUF ? ln : (uint32_t)LBUF;
    uint32_t* sk = ws + OFF_PAIR + (size_t)bid * (2 * LBUF);
    for (uint32_t i = t; i < m; i += 256) {
        sk[i] = lkey[i];
        sk[LBUF + i] = lidx[i];
    }
}

// Kernel 2, one block per row: compute the EXACT threshold key.
// Valid path: gather candidate keys to LDS, two-level radix-select
// (rank = KSEL - above). Invalid path: 3-pass histogram select over the row.
__global__ __launch_bounds__(256) void select_thr(const uint32_t* __restrict__ x,
                                                  uint32_t* __restrict__ ws) {
    __shared__ uint32_t ckey[NCAND_MAX];  // 48 KB; fallback reuses [0..4096) as hist
    __shared__ uint32_t h[1024];
    __shared__ uint32_t sc[256];
    __shared__ uint32_t soff[MBPR + 1];
    __shared__ uint32_t scnt_s[MBPR];
    __shared__ uint32_t acnt_s[MBPR];
    __shared__ uint32_t bc[3];
    const int row = blockIdx.x, t = threadIdx.x;

    if (t < MBPR) {
        scnt_s[t] = ws[OFF_SCNT + (size_t)row * MBPR + t];
        acnt_s[t] = ws[OFF_ACNT + (size_t)row * MBPR + t];
    }
    __syncthreads();
    if (t == 0) {
        uint32_t acc = 0, mx = 0, ab = 0;
        for (int s = 0; s < MBPR; ++s) {
            uint32_t c = scnt_s[s];
            soff[s] = acc;
            if (c > mx) mx = c;
            acc += c;
            ab += acnt_s[s];
        }
        soff[MBPR] = acc;
        bc[0] = acc;  // n candidates
        bc[1] = ab;   // count strictly above bucket
        bc[2] = (mx <= (uint32_t)LBUF && acc <= NCAND_MAX &&
                 ab < KSEL && ab + acc >= KSEL) ? 1u : 0u;
    }
    __syncthreads();
    const uint32_t n = bc[0], above = bc[1], valid = bc[2];

    if (valid) {
        const uint32_t k = KSEL - above;  // rank among candidates, 1-based
        for (int s = 0; s < MBPR; ++s) {
            uint32_t cnt = soff[s + 1] - soff[s];
            const uint32_t* sk = ws + OFF_PAIR + ((size_t)row * MBPR + s) * (2 * LBUF);
            for (uint32_t i = t; i < cnt; i += 256) ckey[soff[s] + i] = sk[i];
        }
        // Level 1: bits 19..10
        for (int i = t; i < 1024; i += 256) h[i] = 0;
        __syncthreads();
        for (uint32_t i = t; i < n; i += 256) atomicAdd(&h[(ckey[i] >> 10) & 0x3FFu], 1u);
        __syncthreads();
        {
            int hi = 1023 - t * 4;
            uint32_t s = 0;
            for (int j = 0; j < 4; ++j) s += h[hi - j];
            sc[t] = s;
            __syncthreads();
            for (int off = 1; off < 256; off <<= 1) {
                uint32_t v = (t >= off) ? sc[t - off] : 0u;
                __syncthreads();
                sc[t] += v;
                __syncthreads();
            }
            uint32_t excl = sc[t] - s;
            if (excl < k && excl + s >= k) {
                uint32_t cc = excl;
                for (int j = 0; j < 4; ++j) {
                    int bin = hi - j;
                    uint32_t hb = h[bin];
                    cc += hb;
                    if (cc >= k) { bc[0] = (uint32_t)bin; bc[1] = k - (cc - hb); break; }
                }
            }
        }
        __syncthreads();
        uint32_t b1 = bc[0], k2 = bc[1];
        __syncthreads();
        // Level 2: bits 9..0
        for (int i = t; i < 1024; i += 256) h[i] = 0;
        __syncthreads();
        for (uint32_t i = t; i < n; i += 256) {
            uint32_t u = ckey[i];
            if (((u >> 10) & 0x3FFu) == b1) atomicAdd(&h[u & 0x3FFu], 1u);
        }
        __syncthreads();
        {
            int hi = 1023 - t * 4;
            uint32_t s = 0;
            for (int j = 0; j < 4; ++j) s += h[hi - j];
            sc[t] = s;
            __syncthreads();
            for (int off = 1; off < 256; off <<= 1) {
                uint32_t v = (t >= off) ? sc[t - off] : 0u;
                __syncthreads();
                sc[t] += v;
                __syncthreads();
            }
            uint32_t excl = sc[t] - s;
            if (excl < k2 && excl + s >= k2) {
                uint32_t cc = excl;
                for (int j = 0; j < 4; ++j) {
                    int bin = hi - j;
                    uint32_t hb = h[bin];
                    cc += hb;
                    if (cc >= k2) {
                        ws[OFF_THR + row] = (PRED_B << 20) | (b1 << 10) | (uint32_t)bin;
                        break;
                    }
                }
            }
        }
        return;
    }

    // ---------- exact fallback (prediction failed; any-data correct) ----------
    const uint4* px = (const uint4*)(x + (size_t)row * D);
    uint32_t* h4k = ckey;  // reuse 16 KB of ckey as 4096-bin hist

    for (int i = t; i < 4096; i += 256) h4k[i] = 0;
    __syncthreads();
    for (int i = t; i < D / 4; i += 256) {
        uint4 v = px[i];
        atomicAdd(&h4k[mono(v.x) >> 20], 1u);
        atomicAdd(&h4k[mono(v.y) >> 20], 1u);
        atomicAdd(&h4k[mono(v.z) >> 20], 1u);
        atomicAdd(&h4k[mono(v.w) >> 20], 1u);
    }
    __syncthreads();
    {
        int hi = 4095 - t * 16;
        uint32_t loc[16];
        uint32_t s = 0;
#pragma unroll
        for (int j = 0; j < 16; ++j) { loc[j] = h4k[hi - j]; s += loc[j]; }
        sc[t] = s;
        __syncthreads();
        for (int off = 1; off < 256; off <<= 1) {
            uint32_t v = (t >= off) ? sc[t - off] : 0u;
            __syncthreads();
            sc[t] += v;
            __syncthreads();
        }
        uint32_t excl = sc[t] - s;
        if (excl < KSEL && excl + s >= KSEL) {
            uint32_t c = excl;
            for (int j = 0; j < 16; ++j) {
                c += loc[j];
                if (c >= KSEL) { bc[0] = (uint32_t)(hi - j); bc[1] = KSEL - (c - loc[j]); break; }
            }
        }
    }
    __syncthreads();
    const uint32_t B = bc[0], r1 = bc[1];
    __syncthreads();

    for (int i = t; i < 1024; i += 256) h[i] = 0;
    __syncthreads();
    for (int i = t; i < D / 4; i += 256) {
        uint4 v = px[i];
        uint32_t u;
        u = mono(v.x); if ((u >> 20) == B) atomicAdd(&h[(u >> 10) & 0x3FFu], 1u);
        u = mono(v.y); if ((u >> 20) == B) atomicAdd(&h[(u >> 10) & 0x3FFu], 1u);
        u = mono(v.z); if ((u >> 20) == B) atomicAdd(&h[(u >> 10) & 0x3FFu], 1u);
        u = mono(v.w); if ((u >> 20) == B) atomicAdd(&h[(u >> 10) & 0x3FFu], 1u);
    }
    __syncthreads();
    {
        int hi = 1023 - t * 4;
        uint32_t s = 0;
        for (int j = 0; j < 4; ++j) s += h[hi - j];
        sc[t] = s;
        __syncthreads();
        for (int off = 1; off < 256; off <<= 1) {
            uint32_t v = (t >= off) ? sc[t - off] : 0u;
            __syncthreads();
            sc[t] += v;
            __syncthreads();
        }
        uint32_t excl = sc[t] - s;
        if (excl < r1 && excl + s >= r1) {
            uint32_t cc = excl;
            for (int j = 0; j < 4; ++j) {
                int bin = hi - j;
                uint32_t hb = h[bin];
                cc += hb;
                if (cc >= r1) { bc[0] = (uint32_t)bin; bc[1] = r1 - (cc - hb); break; }
            }
        }
    }
    __syncthreads();
    const uint32_t pref22 = (B << 10) | bc[0];
    const uint32_t r2 = bc[1];
    __syncthreads();

    for (int i = t; i < 1024; i += 256) h[i] = 0;
    __syncthreads();
    for (int i = t; i < D / 4; i += 256) {
        uint4 v = px[i];
        uint32_t u;
        u = mono(v.x); if ((u >> 10) == pref22) atomicAdd(&h[u & 0x3FFu], 1u);
        u = mono(v.y); if ((u >> 10) == pref22) atomicAdd(&h[u & 0x3FFu], 1u);
        u = mono(v.z); if ((u >> 10) == pref22) atomicAdd(&h[u & 0x3FFu], 1u);
        u = mono(v.w); if ((u >> 10) == pref22) atomicAdd(&h[u & 0x3FFu], 1u);
    }
    __syncthreads();
    {
        int hi = 1023 - t * 4;
        uint32_t s = 0;
        for (int j = 0; j < 4; ++j) s += h[hi - j];
        sc[t] = s;
        __syncthreads();
        for (int off = 1; off < 256; off <<= 1) {
            uint32_t v = (t >= off) ? sc[t - off] : 0u;
            __syncthreads();
            sc[t] += v;
            __syncthreads();
        }
        uint32_t excl = sc[t] - s;
        if (excl < r2 && excl + s >= r2) {
            uint32_t cc = excl;
            for (int j = 0; j < 4; ++j) {
                int bin = hi - j;
                uint32_t hb = h[bin];
                cc += hb;
                if (cc >= r2) { ws[OFF_THR + row] = (pref22 << 10) | (uint32_t)bin; break; }
            }
        }
    }
}

// Kernel 3: pure streaming masked copy against the EXACT per-row threshold.
__global__ __launch_bounds__(256) void mask_final(const uint32_t* __restrict__ x,
                                                  float* __restrict__ out,
                                                  const uint32_t* __restrict__ ws) {
    const int bid = blockIdx.x;
    const int row = bid / MBPR, chunk = bid % MBPR, t = threadIdx.x;
    const uint32_t tk = ws[OFF_THR + row];
    const uint4* __restrict__ p = (const uint4*)(x + (size_t)row * D + (size_t)chunk * MCHUNK);
    f32x4* __restrict__ o = (f32x4*)(out + (size_t)row * D + (size_t)chunk * MCHUNK);
    for (int i = t; i < MCHUNK / 4; i += 256) {
        uint4 v = p[i];
        f32x4 ov;
        ov[0] = (mono(v.x) < tk) ? __uint_as_float(v.x) : 0.0f;
        ov[1] = (mono(v.y) < tk) ? __uint_as_float(v.y) : 0.0f;
        ov[2] = (mono(v.z) < tk) ? __uint_as_float(v.z) : 0.0f;
        ov[3] = (mono(v.w) < tk) ? __uint_as_float(v.w) : 0.0f;
        __builtin_nontemporal_store(ov, &o[i]);
    }
}

extern "C" void kernel_launch(void* const* d_in, const int* in_sizes, int n_in,
                              void* d_out, int out_size, void* d_ws, size_t ws_size,
                              hipStream_t stream) {
    (void)in_sizes; (void)n_in; (void)out_size; (void)ws_size;
    const uint32_t* xu = (const uint32_t*)d_in[0];
    float* outp = (float*)d_out;
    uint32_t* ws = (uint32_t*)d_ws;

    // MEASUREMENT ROUND: cand_scan replicated x3 (idempotent) to expose its
    // steady-state cost: dur - 97.3 = 2*c_warm + 2*bnd.
    cand_scan<<<ROWS * MBPR, 256, 0, stream>>>(xu, ws);
    cand_scan<<<ROWS * MBPR, 256, 0, stream>>>(xu, ws);
    cand_scan<<<ROWS * MBPR, 256, 0, stream>>>(xu, ws);
    select_thr<<<ROWS, 256, 0, stream>>>(xu, ws);
    mask_final<<<ROWS * MBPR, 256, 0, stream>>>(xu, outp, ws);
}

// Round 15
// 98.160 us; speedup vs baseline: 1.4469x; 1.4469x over previous
//
#include <hip/hip_runtime.h>
#include <stdint.h>

// Problem constants
constexpr int ROWS = 64;
constexpr int D = 1 << 19;             // 524288 per row
constexpr uint32_t KSEL = 52428;       // int(0.1 * D)
constexpr int MBPR = 32;               // blocks per row for streaming kernels
constexpr int MCHUNK = D / MBPR;       // 16384 elements per block
constexpr int LBUF = 896;              // per-block slot cap (expected ~352, +29 sigma)
constexpr uint32_t PRED_B = 0xBFAu;    // key bucket of floats [1.25, 1.375);
                                       // K-th largest = 1.2816 +- 0.0024 (13/39 sigma margin)
constexpr uint32_t NCAND_MAX = 12288;  // per-row candidate cap (expected ~11.3K)

// Workspace layout (u32 words). No zeroing needed: counts plain-stored fresh
// every call; slots read only up to their stored count; thr rewritten always.
constexpr size_t OFF_SCNT = 0;         // [2048] per-block candidate count (raw)
constexpr size_t OFF_ACNT = 2048;      // [2048] per-block above-bucket count
constexpr size_t OFF_THR  = 4096;      // [64] exact threshold key per row
constexpr size_t OFF_PAIR = 4160;      // [2048][2*LBUF]: keys[LBUF] then idx[LBUF]

typedef float f32x4 __attribute__((ext_vector_type(4)));

// Monotonic key: larger float -> larger uint
__device__ __forceinline__ uint32_t mono(uint32_t f) {
    uint32_t m = (uint32_t)((int32_t)f >> 31) | 0x80000000u;
    return f ^ m;
}

// Kernel 1 (read-only): per-block candidate collection (bucket == PRED_B)
// + above-bucket count. Measured R14: ~22 us (L3-warm read).
__global__ __launch_bounds__(256) void cand_scan(const uint32_t* __restrict__ x,
                                                 uint32_t* __restrict__ ws) {
    __shared__ uint32_t lkey[LBUF];
    __shared__ uint32_t lidx[LBUF];
    __shared__ uint32_t red[256];
    __shared__ uint32_t ln;
    if (threadIdx.x == 0) ln = 0;
    __syncthreads();
    const int bid = blockIdx.x;
    const int row = bid / MBPR, chunk = bid % MBPR, t = threadIdx.x;
    const uint4* __restrict__ p = (const uint4*)(x + (size_t)row * D + (size_t)chunk * MCHUNK);
    uint32_t above = 0;
    for (int i = t; i < MCHUNK / 4; i += 256) {
        uint4 v = p[i];
        uint32_t idx0 = (uint32_t)chunk * MCHUNK + (uint32_t)i * 4;
#define CLS(comp, j)                                                       \
        {                                                                  \
            uint32_t u = mono(comp);                                       \
            uint32_t bu = u >> 20;                                         \
            above += (bu > PRED_B);                                        \
            if (bu == PRED_B) {                                            \
                uint32_t s = atomicAdd(&ln, 1u);                           \
                if (s < (uint32_t)LBUF) { lkey[s] = u; lidx[s] = idx0 + j; } \
            }                                                              \
        }
        CLS(v.x, 0) CLS(v.y, 1) CLS(v.z, 2) CLS(v.w, 3)
#undef CLS
    }
    red[t] = above;
    __syncthreads();
    for (int off = 128; off > 0; off >>= 1) {
        if (t < off) red[t] += red[t + off];
        __syncthreads();
    }
    if (t == 0) {
        ws[OFF_SCNT + bid] = ln;       // raw count (may exceed LBUF -> fallback)
        ws[OFF_ACNT + bid] = red[0];
    }
    uint32_t m = ln < (uint32_t)LBUF ? ln : (uint32_t)LBUF;
    uint32_t* sk = ws + OFF_PAIR + (size_t)bid * (2 * LBUF);
    for (uint32_t i = t; i < m; i += 256) {
        sk[i] = lkey[i];
        sk[LBUF + i] = lidx[i];
    }
}

// Kernel 2, one block per row: compute the EXACT threshold key.
// Valid path: gather candidate keys to LDS, two-level radix-select
// (rank = KSEL - above). Invalid path: 3-pass histogram select over the row.
__global__ __launch_bounds__(256) void select_thr(const uint32_t* __restrict__ x,
                                                  uint32_t* __restrict__ ws) {
    __shared__ uint32_t ckey[NCAND_MAX];  // 48 KB; fallback reuses [0..4096) as hist
    __shared__ uint32_t h[1024];
    __shared__ uint32_t sc[256];
    __shared__ uint32_t soff[MBPR + 1];
    __shared__ uint32_t scnt_s[MBPR];
    __shared__ uint32_t acnt_s[MBPR];
    __shared__ uint32_t bc[3];
    const int row = blockIdx.x, t = threadIdx.x;

    if (t < MBPR) {
        scnt_s[t] = ws[OFF_SCNT + (size_t)row * MBPR + t];
        acnt_s[t] = ws[OFF_ACNT + (size_t)row * MBPR + t];
    }
    __syncthreads();
    if (t == 0) {
        uint32_t acc = 0, mx = 0, ab = 0;
        for (int s = 0; s < MBPR; ++s) {
            uint32_t c = scnt_s[s];
            soff[s] = acc;
            if (c > mx) mx = c;
            acc += c;
            ab += acnt_s[s];
        }
        soff[MBPR] = acc;
        bc[0] = acc;  // n candidates
        bc[1] = ab;   // count strictly above bucket
        bc[2] = (mx <= (uint32_t)LBUF && acc <= NCAND_MAX &&
                 ab < KSEL && ab + acc >= KSEL) ? 1u : 0u;
    }
    __syncthreads();
    const uint32_t n = bc[0], above = bc[1], valid = bc[2];

    if (valid) {
        const uint32_t k = KSEL - above;  // rank among candidates, 1-based
        for (int s = 0; s < MBPR; ++s) {
            uint32_t cnt = soff[s + 1] - soff[s];
            const uint32_t* sk = ws + OFF_PAIR + ((size_t)row * MBPR + s) * (2 * LBUF);
            for (uint32_t i = t; i < cnt; i += 256) ckey[soff[s] + i] = sk[i];
        }
        // Level 1: bits 19..10
        for (int i = t; i < 1024; i += 256) h[i] = 0;
        __syncthreads();
        for (uint32_t i = t; i < n; i += 256) atomicAdd(&h[(ckey[i] >> 10) & 0x3FFu], 1u);
        __syncthreads();
        {
            int hi = 1023 - t * 4;
            uint32_t s = 0;
            for (int j = 0; j < 4; ++j) s += h[hi - j];
            sc[t] = s;
            __syncthreads();
            for (int off = 1; off < 256; off <<= 1) {
                uint32_t v = (t >= off) ? sc[t - off] : 0u;
                __syncthreads();
                sc[t] += v;
                __syncthreads();
            }
            uint32_t excl = sc[t] - s;
            if (excl < k && excl + s >= k) {
                uint32_t cc = excl;
                for (int j = 0; j < 4; ++j) {
                    int bin = hi - j;
                    uint32_t hb = h[bin];
                    cc += hb;
                    if (cc >= k) { bc[0] = (uint32_t)bin; bc[1] = k - (cc - hb); break; }
                }
            }
        }
        __syncthreads();
        uint32_t b1 = bc[0], k2 = bc[1];
        __syncthreads();
        // Level 2: bits 9..0
        for (int i = t; i < 1024; i += 256) h[i] = 0;
        __syncthreads();
        for (uint32_t i = t; i < n; i += 256) {
            uint32_t u = ckey[i];
            if (((u >> 10) & 0x3FFu) == b1) atomicAdd(&h[u & 0x3FFu], 1u);
        }
        __syncthreads();
        {
            int hi = 1023 - t * 4;
            uint32_t s = 0;
            for (int j = 0; j < 4; ++j) s += h[hi - j];
            sc[t] = s;
            __syncthreads();
            for (int off = 1; off < 256; off <<= 1) {
                uint32_t v = (t >= off) ? sc[t - off] : 0u;
                __syncthreads();
                sc[t] += v;
                __syncthreads();
            }
            uint32_t excl = sc[t] - s;
            if (excl < k2 && excl + s >= k2) {
                uint32_t cc = excl;
                for (int j = 0; j < 4; ++j) {
                    int bin = hi - j;
                    uint32_t hb = h[bin];
                    cc += hb;
                    if (cc >= k2) {
                        ws[OFF_THR + row] = (PRED_B << 20) | (b1 << 10) | (uint32_t)bin;
                        break;
                    }
                }
            }
        }
        return;
    }

    // ---------- exact fallback (prediction failed; any-data correct) ----------
    const uint4* px = (const uint4*)(x + (size_t)row * D);
    uint32_t* h4k = ckey;  // reuse 16 KB of ckey as 4096-bin hist

    for (int i = t; i < 4096; i += 256) h4k[i] = 0;
    __syncthreads();
    for (int i = t; i < D / 4; i += 256) {
        uint4 v = px[i];
        atomicAdd(&h4k[mono(v.x) >> 20], 1u);
        atomicAdd(&h4k[mono(v.y) >> 20], 1u);
        atomicAdd(&h4k[mono(v.z) >> 20], 1u);
        atomicAdd(&h4k[mono(v.w) >> 20], 1u);
    }
    __syncthreads();
    {
        int hi = 4095 - t * 16;
        uint32_t loc[16];
        uint32_t s = 0;
#pragma unroll
        for (int j = 0; j < 16; ++j) { loc[j] = h4k[hi - j]; s += loc[j]; }
        sc[t] = s;
        __syncthreads();
        for (int off = 1; off < 256; off <<= 1) {
            uint32_t v = (t >= off) ? sc[t - off] : 0u;
            __syncthreads();
            sc[t] += v;
            __syncthreads();
        }
        uint32_t excl = sc[t] - s;
        if (excl < KSEL && excl + s >= KSEL) {
            uint32_t c = excl;
            for (int j = 0; j < 16; ++j) {
                c += loc[j];
                if (c >= KSEL) { bc[0] = (uint32_t)(hi - j); bc[1] = KSEL - (c - loc[j]); break; }
            }
        }
    }
    __syncthreads();
    const uint32_t B = bc[0], r1 = bc[1];
    __syncthreads();

    for (int i = t; i < 1024; i += 256) h[i] = 0;
    __syncthreads();
    for (int i = t; i < D / 4; i += 256) {
        uint4 v = px[i];
        uint32_t u;
        u = mono(v.x); if ((u >> 20) == B) atomicAdd(&h[(u >> 10) & 0x3FFu], 1u);
        u = mono(v.y); if ((u >> 20) == B) atomicAdd(&h[(u >> 10) & 0x3FFu], 1u);
        u = mono(v.z); if ((u >> 20) == B) atomicAdd(&h[(u >> 10) & 0x3FFu], 1u);
        u = mono(v.w); if ((u >> 20) == B) atomicAdd(&h[(u >> 10) & 0x3FFu], 1u);
    }
    __syncthreads();
    {
        int hi = 1023 - t * 4;
        uint32_t s = 0;
        for (int j = 0; j < 4; ++j) s += h[hi - j];
        sc[t] = s;
        __syncthreads();
        for (int off = 1; off < 256; off <<= 1) {
            uint32_t v = (t >= off) ? sc[t - off] : 0u;
            __syncthreads();
            sc[t] += v;
            __syncthreads();
        }
        uint32_t excl = sc[t] - s;
        if (excl < r1 && excl + s >= r1) {
            uint32_t cc = excl;
            for (int j = 0; j < 4; ++j) {
                int bin = hi - j;
                uint32_t hb = h[bin];
                cc += hb;
                if (cc >= r1) { bc[0] = (uint32_t)bin; bc[1] = r1 - (cc - hb); break; }
            }
        }
    }
    __syncthreads();
    const uint32_t pref22 = (B << 10) | bc[0];
    const uint32_t r2 = bc[1];
    __syncthreads();

    for (int i = t; i < 1024; i += 256) h[i] = 0;
    __syncthreads();
    for (int i = t; i < D / 4; i += 256) {
        uint4 v = px[i];
        uint32_t u;
        u = mono(v.x); if ((u >> 10) == pref22) atomicAdd(&h[u & 0x3FFu], 1u);
        u = mono(v.y); if ((u >> 10) == pref22) atomicAdd(&h[u & 0x3FFu], 1u);
        u = mono(v.z); if ((u >> 10) == pref22) atomicAdd(&h[u & 0x3FFu], 1u);
        u = mono(v.w); if ((u >> 10) == pref22) atomicAdd(&h[u & 0x3FFu], 1u);
    }
    __syncthreads();
    {
        int hi = 1023 - t * 4;
        uint32_t s = 0;
        for (int j = 0; j < 4; ++j) s += h[hi - j];
        sc[t] = s;
        __syncthreads();
        for (int off = 1; off < 256; off <<= 1) {
            uint32_t v = (t >= off) ? sc[t - off] : 0u;
            __syncthreads();
            sc[t] += v;
            __syncthreads();
        }
        uint32_t excl = sc[t] - s;
        if (excl < r2 && excl + s >= r2) {
            uint32_t cc = excl;
            for (int j = 0; j < 4; ++j) {
                int bin = hi - j;
                uint32_t hb = h[bin];
                cc += hb;
                if (cc >= r2) { ws[OFF_THR + row] = (pref22 << 10) | (uint32_t)bin; break; }
            }
        }
    }
}

// Kernel 3: pure streaming masked copy. A/B template: USE_NT selects
// nontemporal vs regular stores; processes rows [row_base, row_base+32).
template <bool USE_NT>
__global__ __launch_bounds__(256) void mask_final_t(const uint32_t* __restrict__ x,
                                                    float* __restrict__ out,
                                                    const uint32_t* __restrict__ ws,
                                                    int row_base) {
    const int bid = row_base * MBPR + blockIdx.x;
    const int row = bid / MBPR, chunk = bid % MBPR, t = threadIdx.x;
    const uint32_t tk = ws[OFF_THR + row];
    const uint4* __restrict__ p = (const uint4*)(x + (size_t)row * D + (size_t)chunk * MCHUNK);
    f32x4* __restrict__ o = (f32x4*)(out + (size_t)row * D + (size_t)chunk * MCHUNK);
    for (int i = t; i < MCHUNK / 4; i += 256) {
        uint4 v = p[i];
        f32x4 ov;
        ov[0] = (mono(v.x) < tk) ? __uint_as_float(v.x) : 0.0f;
        ov[1] = (mono(v.y) < tk) ? __uint_as_float(v.y) : 0.0f;
        ov[2] = (mono(v.z) < tk) ? __uint_as_float(v.z) : 0.0f;
        ov[3] = (mono(v.w) < tk) ? __uint_as_float(v.w) : 0.0f;
        if constexpr (USE_NT)
            __builtin_nontemporal_store(ov, &o[i]);
        else
            o[i] = ov;
    }
}

extern "C" void kernel_launch(void* const* d_in, const int* in_sizes, int n_in,
                              void* d_out, int out_size, void* d_ws, size_t ws_size,
                              hipStream_t stream) {
    (void)in_sizes; (void)n_in; (void)out_size; (void)ws_size;
    const uint32_t* xu = (const uint32_t*)d_in[0];
    float* outp = (float*)d_out;
    uint32_t* ws = (uint32_t*)d_ws;

    cand_scan<<<ROWS * MBPR, 256, 0, stream>>>(xu, ws);
    select_thr<<<ROWS, 256, 0, stream>>>(xu, ws);
    // Within-probe A/B on the pure copy: rows 0-31 NT, rows 32-63 regular.
    mask_final_t<true><<<(ROWS / 2) * MBPR, 256, 0, stream>>>(xu, outp, ws, 0);
    mask_final_t<false><<<(ROWS / 2) * MBPR, 256, 0, stream>>>(xu, outp, ws, ROWS / 2);
}

// Round 16
// 95.615 us; speedup vs baseline: 1.4855x; 1.0266x over previous
//
#include <hip/hip_runtime.h>
#include <stdint.h>

// Problem constants
constexpr int ROWS = 64;
constexpr int D = 1 << 19;             // 524288 per row
constexpr uint32_t KSEL = 52428;       // int(0.1 * D)
constexpr int MBPR = 32;               // blocks per row, cand_scan
constexpr int MCHUNK = D / MBPR;       // 16384 elements per block
constexpr int LBUF = 896;              // per-block slot cap (expected ~352, +29 sigma)
constexpr uint32_t PRED_B = 0xBFAu;    // key bucket of floats [1.25, 1.375);
                                       // K-th largest = 1.2816 +- 0.0024 (13/39 sigma margin)
constexpr uint32_t NCAND_MAX = 12288;  // per-row candidate cap (expected ~11.3K)

// mask_final geometry: 8 uint4 per thread, fully unrolled batch
constexpr int FBPR = 64;               // mask blocks per row
constexpr int FCHUNK_V4 = (D / 4) / FBPR;  // 2048 uint4 per block

// Workspace layout (u32 words). No zeroing needed: counts plain-stored fresh
// every call; slots read only up to their stored count; thr rewritten always.
constexpr size_t OFF_SCNT = 0;         // [2048] per-block candidate count (raw)
constexpr size_t OFF_ACNT = 2048;      // [2048] per-block above-bucket count
constexpr size_t OFF_THR  = 4096;      // [64] exact threshold key per row
constexpr size_t OFF_PAIR = 4160;      // [2048][2*LBUF]: keys[LBUF] then idx[LBUF]

typedef float f32x4 __attribute__((ext_vector_type(4)));

// Monotonic key: larger float -> larger uint
__device__ __forceinline__ uint32_t mono(uint32_t f) {
    uint32_t m = (uint32_t)((int32_t)f >> 31) | 0x80000000u;
    return f ^ m;
}

// Kernel 1 (read-only): per-block candidate collection (bucket == PRED_B)
// + above-bucket count. Measured R14: ~22 us (near read ceiling).
__global__ __launch_bounds__(256) void cand_scan(const uint32_t* __restrict__ x,
                                                 uint32_t* __restrict__ ws) {
    __shared__ uint32_t lkey[LBUF];
    __shared__ uint32_t lidx[LBUF];
    __shared__ uint32_t red[256];
    __shared__ uint32_t ln;
    if (threadIdx.x == 0) ln = 0;
    __syncthreads();
    const int bid = blockIdx.x;
    const int row = bid / MBPR, chunk = bid % MBPR, t = threadIdx.x;
    const uint4* __restrict__ p = (const uint4*)(x + (size_t)row * D + (size_t)chunk * MCHUNK);
    uint32_t above = 0;
    for (int i = t; i < MCHUNK / 4; i += 256) {
        uint4 v = p[i];
        uint32_t idx0 = (uint32_t)chunk * MCHUNK + (uint32_t)i * 4;
#define CLS(comp, j)                                                       \
        {                                                                  \
            uint32_t u = mono(comp);                                       \
            uint32_t bu = u >> 20;                                         \
            above += (bu > PRED_B);                                        \
            if (bu == PRED_B) {                                            \
                uint32_t s = atomicAdd(&ln, 1u);                           \
                if (s < (uint32_t)LBUF) { lkey[s] = u; lidx[s] = idx0 + j; } \
            }                                                              \
        }
        CLS(v.x, 0) CLS(v.y, 1) CLS(v.z, 2) CLS(v.w, 3)
#undef CLS
    }
    red[t] = above;
    __syncthreads();
    for (int off = 128; off > 0; off >>= 1) {
        if (t < off) red[t] += red[t + off];
        __syncthreads();
    }
    if (t == 0) {
        ws[OFF_SCNT + bid] = ln;       // raw count (may exceed LBUF -> fallback)
        ws[OFF_ACNT + bid] = red[0];
    }
    uint32_t m = ln < (uint32_t)LBUF ? ln : (uint32_t)LBUF;
    uint32_t* sk = ws + OFF_PAIR + (size_t)bid * (2 * LBUF);
    for (uint32_t i = t; i < m; i += 256) {
        sk[i] = lkey[i];
        sk[LBUF + i] = lidx[i];
    }
}

// Kernel 2, one block per row: compute the EXACT threshold key.
// Valid path: gather candidate keys to LDS, two-level radix-select
// (rank = KSEL - above). Invalid path: 3-pass histogram select over the row.
__global__ __launch_bounds__(256) void select_thr(const uint32_t* __restrict__ x,
                                                  uint32_t* __restrict__ ws) {
    __shared__ uint32_t ckey[NCAND_MAX];  // 48 KB; fallback reuses [0..4096) as hist
    __shared__ uint32_t h[1024];
    __shared__ uint32_t sc[256];
    __shared__ uint32_t soff[MBPR + 1];
    __shared__ uint32_t scnt_s[MBPR];
    __shared__ uint32_t acnt_s[MBPR];
    __shared__ uint32_t bc[3];
    const int row = blockIdx.x, t = threadIdx.x;

    if (t < MBPR) {
        scnt_s[t] = ws[OFF_SCNT + (size_t)row * MBPR + t];
        acnt_s[t] = ws[OFF_ACNT + (size_t)row * MBPR + t];
    }
    __syncthreads();
    if (t == 0) {
        uint32_t acc = 0, mx = 0, ab = 0;
        for (int s = 0; s < MBPR; ++s) {
            uint32_t c = scnt_s[s];
            soff[s] = acc;
            if (c > mx) mx = c;
            acc += c;
            ab += acnt_s[s];
        }
        soff[MBPR] = acc;
        bc[0] = acc;  // n candidates
        bc[1] = ab;   // count strictly above bucket
        bc[2] = (mx <= (uint32_t)LBUF && acc <= NCAND_MAX &&
                 ab < KSEL && ab + acc >= KSEL) ? 1u : 0u;
    }
    __syncthreads();
    const uint32_t n = bc[0], above = bc[1], valid = bc[2];

    if (valid) {
        const uint32_t k = KSEL - above;  // rank among candidates, 1-based
        for (int s = 0; s < MBPR; ++s) {
            uint32_t cnt = soff[s + 1] - soff[s];
            const uint32_t* sk = ws + OFF_PAIR + ((size_t)row * MBPR + s) * (2 * LBUF);
            for (uint32_t i = t; i < cnt; i += 256) ckey[soff[s] + i] = sk[i];
        }
        // Level 1: bits 19..10
        for (int i = t; i < 1024; i += 256) h[i] = 0;
        __syncthreads();
        for (uint32_t i = t; i < n; i += 256) atomicAdd(&h[(ckey[i] >> 10) & 0x3FFu], 1u);
        __syncthreads();
        {
            int hi = 1023 - t * 4;
            uint32_t s = 0;
            for (int j = 0; j < 4; ++j) s += h[hi - j];
            sc[t] = s;
            __syncthreads();
            for (int off = 1; off < 256; off <<= 1) {
                uint32_t v = (t >= off) ? sc[t - off] : 0u;
                __syncthreads();
                sc[t] += v;
                __syncthreads();
            }
            uint32_t excl = sc[t] - s;
            if (excl < k && excl + s >= k) {
                uint32_t cc = excl;
                for (int j = 0; j < 4; ++j) {
                    int bin = hi - j;
                    uint32_t hb = h[bin];
                    cc += hb;
                    if (cc >= k) { bc[0] = (uint32_t)bin; bc[1] = k - (cc - hb); break; }
                }
            }
        }
        __syncthreads();
        uint32_t b1 = bc[0], k2 = bc[1];
        __syncthreads();
        // Level 2: bits 9..0
        for (int i = t; i < 1024; i += 256) h[i] = 0;
        __syncthreads();
        for (uint32_t i = t; i < n; i += 256) {
            uint32_t u = ckey[i];
            if (((u >> 10) & 0x3FFu) == b1) atomicAdd(&h[u & 0x3FFu], 1u);
        }
        __syncthreads();
        {
            int hi = 1023 - t * 4;
            uint32_t s = 0;
            for (int j = 0; j < 4; ++j) s += h[hi - j];
            sc[t] = s;
            __syncthreads();
            for (int off = 1; off < 256; off <<= 1) {
                uint32_t v = (t >= off) ? sc[t - off] : 0u;
                __syncthreads();
                sc[t] += v;
                __syncthreads();
            }
            uint32_t excl = sc[t] - s;
            if (excl < k2 && excl + s >= k2) {
                uint32_t cc = excl;
                for (int j = 0; j < 4; ++j) {
                    int bin = hi - j;
                    uint32_t hb = h[bin];
                    cc += hb;
                    if (cc >= k2) {
                        ws[OFF_THR + row] = (PRED_B << 20) | (b1 << 10) | (uint32_t)bin;
                        break;
                    }
                }
            }
        }
        return;
    }

    // ---------- exact fallback (prediction failed; any-data correct) ----------
    const uint4* px = (const uint4*)(x + (size_t)row * D);
    uint32_t* h4k = ckey;  // reuse 16 KB of ckey as 4096-bin hist

    for (int i = t; i < 4096; i += 256) h4k[i] = 0;
    __syncthreads();
    for (int i = t; i < D / 4; i += 256) {
        uint4 v = px[i];
        atomicAdd(&h4k[mono(v.x) >> 20], 1u);
        atomicAdd(&h4k[mono(v.y) >> 20], 1u);
        atomicAdd(&h4k[mono(v.z) >> 20], 1u);
        atomicAdd(&h4k[mono(v.w) >> 20], 1u);
    }
    __syncthreads();
    {
        int hi = 4095 - t * 16;
        uint32_t loc[16];
        uint32_t s = 0;
#pragma unroll
        for (int j = 0; j < 16; ++j) { loc[j] = h4k[hi - j]; s += loc[j]; }
        sc[t] = s;
        __syncthreads();
        for (int off = 1; off < 256; off <<= 1) {
            uint32_t v = (t >= off) ? sc[t - off] : 0u;
            __syncthreads();
            sc[t] += v;
            __syncthreads();
        }
        uint32_t excl = sc[t] - s;
        if (excl < KSEL && excl + s >= KSEL) {
            uint32_t c = excl;
            for (int j = 0; j < 16; ++j) {
                c += loc[j];
                if (c >= KSEL) { bc[0] = (uint32_t)(hi - j); bc[1] = KSEL - (c - loc[j]); break; }
            }
        }
    }
    __syncthreads();
    const uint32_t B = bc[0], r1 = bc[1];
    __syncthreads();

    for (int i = t; i < 1024; i += 256) h[i] = 0;
    __syncthreads();
    for (int i = t; i < D / 4; i += 256) {
        uint4 v = px[i];
        uint32_t u;
        u = mono(v.x); if ((u >> 20) == B) atomicAdd(&h[(u >> 10) & 0x3FFu], 1u);
        u = mono(v.y); if ((u >> 20) == B) atomicAdd(&h[(u >> 10) & 0x3FFu], 1u);
        u = mono(v.z); if ((u >> 20) == B) atomicAdd(&h[(u >> 10) & 0x3FFu], 1u);
        u = mono(v.w); if ((u >> 20) == B) atomicAdd(&h[(u >> 10) & 0x3FFu], 1u);
    }
    __syncthreads();
    {
        int hi = 1023 - t * 4;
        uint32_t s = 0;
        for (int j = 0; j < 4; ++j) s += h[hi - j];
        sc[t] = s;
        __syncthreads();
        for (int off = 1; off < 256; off <<= 1) {
            uint32_t v = (t >= off) ? sc[t - off] : 0u;
            __syncthreads();
            sc[t] += v;
            __syncthreads();
        }
        uint32_t excl = sc[t] - s;
        if (excl < r1 && excl + s >= r1) {
            uint32_t cc = excl;
            for (int j = 0; j < 4; ++j) {
                int bin = hi - j;
                uint32_t hb = h[bin];
                cc += hb;
                if (cc >= r1) { bc[0] = (uint32_t)bin; bc[1] = r1 - (cc - hb); break; }
            }
        }
    }
    __syncthreads();
    const uint32_t pref22 = (B << 10) | bc[0];
    const uint32_t r2 = bc[1];
    __syncthreads();

    for (int i = t; i < 1024; i += 256) h[i] = 0;
    __syncthreads();
    for (int i = t; i < D / 4; i += 256) {
        uint4 v = px[i];
        uint32_t u;
        u = mono(v.x); if ((u >> 10) == pref22) atomicAdd(&h[u & 0x3FFu], 1u);
        u = mono(v.y); if ((u >> 10) == pref22) atomicAdd(&h[u & 0x3FFu], 1u);
        u = mono(v.z); if ((u >> 10) == pref22) atomicAdd(&h[u & 0x3FFu], 1u);
        u = mono(v.w); if ((u >> 10) == pref22) atomicAdd(&h[u & 0x3FFu], 1u);
    }
    __syncthreads();
    {
        int hi = 1023 - t * 4;
        uint32_t s = 0;
        for (int j = 0; j < 4; ++j) s += h[hi - j];
        sc[t] = s;
        __syncthreads();
        for (int off = 1; off < 256; off <<= 1) {
            uint32_t v = (t >= off) ? sc[t - off] : 0u;
            __syncthreads();
            sc[t] += v;
            __syncthreads();
        }
        uint32_t excl = sc[t] - s;
        if (excl < r2 && excl + s >= r2) {
            uint32_t cc = excl;
            for (int j = 0; j < 4; ++j) {
                int bin = hi - j;
                uint32_t hb = h[bin];
                cc += hb;
                if (cc >= r2) { ws[OFF_THR + row] = (pref22 << 10) | (uint32_t)bin; break; }
            }
        }
    }
}

// Kernel 3: streaming masked copy, MLP-maximized. One fully-unrolled batch
// of 8 independent uint4 loads per thread (no loop-carried dependency, no
// LDS, no atomics) -> 8 loads in flight per wave, then 8 NT stores.
__global__ __launch_bounds__(256) void mask_final(const uint32_t* __restrict__ x,
                                                  float* __restrict__ out,
                                                  const uint32_t* __restrict__ ws) {
    const int bid = blockIdx.x;                 // 4096 blocks
    const int row = bid / FBPR, chunk = bid % FBPR, t = threadIdx.x;
    const uint32_t tk = ws[OFF_THR + row];
    const uint4* __restrict__ p =
        (const uint4*)(x + (size_t)row * D) + (size_t)chunk * FCHUNK_V4;
    f32x4* __restrict__ o =
        (f32x4*)(out + (size_t)row * D) + (size_t)chunk * FCHUNK_V4;

    uint4 v[8];
#pragma unroll
    for (int k = 0; k < 8; ++k) v[k] = p[t + k * 256];   // 8 loads in flight

    f32x4 ov[8];
#pragma unroll
    for (int k = 0; k < 8; ++k) {
        ov[k][0] = (mono(v[k].x) < tk) ? __uint_as_float(v[k].x) : 0.0f;
        ov[k][1] = (mono(v[k].y) < tk) ? __uint_as_float(v[k].y) : 0.0f;
        ov[k][2] = (mono(v[k].z) < tk) ? __uint_as_float(v[k].z) : 0.0f;
        ov[k][3] = (mono(v[k].w) < tk) ? __uint_as_float(v[k].w) : 0.0f;
    }
#pragma unroll
    for (int k = 0; k < 8; ++k)
        __builtin_nontemporal_store(ov[k], &o[t + k * 256]);
}

extern "C" void kernel_launch(void* const* d_in, const int* in_sizes, int n_in,
                              void* d_out, int out_size, void* d_ws, size_t ws_size,
                              hipStream_t stream) {
    (void)in_sizes; (void)n_in; (void)out_size; (void)ws_size;
    const uint32_t* xu = (const uint32_t*)d_in[0];
    float* outp = (float*)d_out;
    uint32_t* ws = (uint32_t*)d_ws;

    cand_scan<<<ROWS * MBPR, 256, 0, stream>>>(xu, ws);
    select_thr<<<ROWS, 256, 0, stream>>>(xu, ws);
    mask_final<<<ROWS * FBPR, 256, 0, stream>>>(xu, outp, ws);
}